// Round 4
// baseline (9483.206 us; speedup 1.0000x reference)
//
#include <hip/hip_runtime.h>

typedef unsigned short u16;
typedef __attribute__((ext_vector_type(8))) short bf16x8;
typedef __attribute__((ext_vector_type(4))) float f32x4;

#define C_  64
#define D_  64
#define H_  128
#define W_  128
#define HW_ 16384
#define S_  1048576
#define K_  192

union PK { u16 u[8]; bf16x8 v; };

__device__ __forceinline__ float bf2f(u16 u){
  union { unsigned i; float f; } v; v.i = ((unsigned)u) << 16; return v.f;
}
__device__ __forceinline__ u16 f2bf(float f){
  union { unsigned i; float f; } v; v.f = f;
  unsigned r = v.i + 0x7FFFu + ((v.i >> 16) & 1u);  // round-to-nearest-even
  return (u16)(r >> 16);
}
__device__ __forceinline__ float ldx(const float* __restrict__ x, int c, int d, int h, int w){
  if ((unsigned)d < (unsigned)D_ && (unsigned)h < (unsigned)H_ && (unsigned)w < (unsigned)W_)
    return x[(c<<20) + (d<<14) + (h<<7) + w];
  return 0.f;
}

// t_d: 3x3 over (h,w); t_h: 3x3 over (d,w); t_w: 3x3 over (d,h). 19 unique taps.
__device__ __forceinline__ void compute_tri(
    const float* __restrict__ x, int c, int d, int h, int w,
    const float* wd, const float* wh, const float* ww,
    float& td, float& th, float& tw)
{
  float A00=ldx(x,c,d,h-1,w-1), A01=ldx(x,c,d,h-1,w), A02=ldx(x,c,d,h-1,w+1);
  float A10=ldx(x,c,d,h  ,w-1), A11=ldx(x,c,d,h  ,w), A12=ldx(x,c,d,h  ,w+1);
  float A20=ldx(x,c,d,h+1,w-1), A21=ldx(x,c,d,h+1,w), A22=ldx(x,c,d,h+1,w+1);
  float B00=ldx(x,c,d-1,h,w-1), B01=ldx(x,c,d-1,h,w), B02=ldx(x,c,d-1,h,w+1);
  float B20=ldx(x,c,d+1,h,w-1), B21=ldx(x,c,d+1,h,w), B22=ldx(x,c,d+1,h,w+1);
  float C00=ldx(x,c,d-1,h-1,w), C02=ldx(x,c,d-1,h+1,w);
  float C20=ldx(x,c,d+1,h-1,w), C22=ldx(x,c,d+1,h+1,w);
  td = wd[0]*A00+wd[1]*A01+wd[2]*A02+wd[3]*A10+wd[4]*A11+wd[5]*A12+wd[6]*A20+wd[7]*A21+wd[8]*A22;
  th = wh[0]*B00+wh[1]*B01+wh[2]*B02+wh[3]*A10+wh[4]*A11+wh[5]*A12+wh[6]*B20+wh[7]*B21+wh[8]*B22;
  tw = ww[0]*C00+ww[1]*B01+ww[2]*C02+ww[3]*A01+ww[4]*A11+ww[5]*A21+ww[6]*C20+ww[7]*B21+ww[8]*C22;
}

__device__ __forceinline__ float wave_sum(float v){
  #pragma unroll
  for (int off = 32; off > 0; off >>= 1) v += __shfl_down(v, off, 64);
  return v;
}

// Pass 1: depthwise conv outputs -> per-channel sum / sumsq (192 channels). No tensor writes.
__global__ __launch_bounds__(256) void k_dw_stats(
    const float* __restrict__ x, const float* __restrict__ w_d, const float* __restrict__ w_h,
    const float* __restrict__ w_w, const float* __restrict__ b_d, const float* __restrict__ b_h,
    const float* __restrict__ b_w, float* __restrict__ stats)
{
  int d = blockIdx.x, c = blockIdx.y, t = threadIdx.x;
  float wd[9], wh[9], ww[9];
  #pragma unroll
  for (int i=0;i<9;i++){ wd[i]=w_d[c*9+i]; wh[i]=w_h[c*9+i]; ww[i]=w_w[c*9+i]; }
  float bd=b_d[c], bh=b_h[c], bw=b_w[c];
  float s0=0,q0=0,s1=0,q1=0,s2=0,q2=0;
  for (int idx=t; idx<HW_; idx+=256){
    int h = idx>>7, w = idx&127;
    float td,th,tw;
    compute_tri(x,c,d,h,w,wd,wh,ww,td,th,tw);
    td+=bd; th+=bh; tw+=bw;
    s0+=td; q0+=td*td; s1+=th; q1+=th*th; s2+=tw; q2+=tw*tw;
  }
  s0=wave_sum(s0); q0=wave_sum(q0); s1=wave_sum(s1);
  q1=wave_sum(q1); s2=wave_sum(s2); q2=wave_sum(q2);
  if ((t&63)==0){
    atomicAdd(&stats[2*c],         s0); atomicAdd(&stats[2*c+1],         q0);
    atomicAdd(&stats[2*(64+c)],    s1); atomicAdd(&stats[2*(64+c)+1],    q1);
    atomicAdd(&stats[2*(128+c)],   s2); atomicAdd(&stats[2*(128+c)+1],   q2);
  }
}

__global__ void k_finalize(const float* __restrict__ stats, float* __restrict__ mu_rs, int n){
  int i = threadIdx.x;
  if (i < n){
    const float inv = 1.f/1048576.f;
    float mu  = stats[2*i]*inv;
    float var = stats[2*i+1]*inv - mu*mu;
    mu_rs[2*i]   = mu;
    mu_rs[2*i+1] = rsqrtf(var + 1e-5f);
  }
}

// Activation LDS: [p (128 rows)][k padded to 128 elems], bf16, 16B blocks XOR-swizzled by (p&7).
// Row stride 256 B. Block index b_orig in [0,12) -> b = (b_orig&8) | ((b_orig&7) ^ (p&7)).
__device__ __forceinline__ void st_act(u16* a_lds, int p, int b_orig, bf16x8 v){
  int b = (b_orig & 8) | ((b_orig & 7) ^ (p & 7));
  *(bf16x8*)((char*)a_lds + p*256 + b*16) = v;
}
__device__ __forceinline__ bf16x8 ld_act(const u16* a_lds, int p, int b_orig){
  int b = (b_orig & 8) | ((b_orig & 7) ^ (p & 7));
  return *(const bf16x8*)((const char*)a_lds + p*256 + b*16);
}

// Pass 2: conv recompute (lane->w coalesced) -> normalized bf16 acts in LDS [p][k] ->
// MFMA pointwise (M=64 ch, N=128 px, K=192 in two 96-chunks) -> fp32 out + out-channel stats.
// launch_bounds(256,3): cap VGPR ~168 -> 3 blocks/CU. (Cap 128 spilled in an earlier round;
// no cap ballooned to 256 VGPR / 1 block/CU.) sched_barrier(0) between channel iterations
// keeps live ranges short so the cap is met without spills.
__global__ __launch_bounds__(256, 3) void k_pointwise(
    const float* __restrict__ x, const float* __restrict__ w_d, const float* __restrict__ w_h,
    const float* __restrict__ w_w, const float* __restrict__ b_d, const float* __restrict__ b_h,
    const float* __restrict__ b_w, const float* __restrict__ w_pw, const float* __restrict__ b_pw,
    const float* __restrict__ mu_rs, float* __restrict__ stats_out, float* __restrict__ out)
{
  __shared__ __align__(16) u16 a_lds[128*128];   // 32 KB
  __shared__ float cstat[1024];                  // [2*ch + which][8 slots]
  int t = threadIdx.x;
  int lane = t & 63, wave = t >> 6;

  // XCD-chunked swizzle: xcd gets d in [8*xcd, 8*xcd+8), ordered as (4d x 16h) tiles.
  int bid = blockIdx.x;
  int xcd = bid & 7, j = bid >> 3;
  int tile = j >> 6, idx = j & 63;
  int d = (xcd<<3) + ((tile&1)<<2) + (idx>>4);
  int h = ((tile>>1)<<4) + (idx&15);

  for (int i=t; i<1024; i+=256) cstat[i] = 0.f;

  // Accumulators: D[ch][p]. Lane layout (16x16x32): p = p_tile + (lane&15),
  // ch = ch_tile + (lane>>4)*4 + reg. acc[mt][nt], mt: 4 ch-tiles, nt: 2 p-tiles (wave owns 32 px).
  f32x4 acc[4][2];
  #pragma unroll
  for (int mt=0; mt<4; ++mt){
    #pragma unroll
    for (int r=0; r<4; ++r){
      float b = b_pw[(mt<<4) + ((lane>>4)<<2) + r];
      acc[mt][0][r] = b; acc[mt][1][r] = b;
    }
  }

  int pA  = ((wave>>1)<<6) + lane;   // phase-A pixel: waves 0,1 -> 0..63; waves 2,3 -> 64..127
  int cl0 = (wave&1) << 4;           // phase-A channel sub-range within the 32-chunk

  for (int g=0; g<2; ++g){
    if (g) __syncthreads();          // previous chunk's phase-B reads done before overwrite

    // ---- phase A: channels c in [32g+cl0, 32g+cl0+16) for pixel pA ----
    #pragma unroll
    for (int q=0; q<2; ++q){
      PK u0, u1, u2;
      #pragma unroll
      for (int r=0; r<8; ++r){
        int c = (g<<5) + cl0 + (q<<3) + r;
        float wd[9], wh[9], ww[9];
        #pragma unroll
        for (int i=0;i<9;i++){ wd[i]=w_d[c*9+i]; wh[i]=w_h[c*9+i]; ww[i]=w_w[c*9+i]; }
        float td,th,tw;
        compute_tri(x,c,d,h,pA,wd,wh,ww,td,th,tw);
        td += b_d[c]; th += b_h[c]; tw += b_w[c];
        float a0=(td-mu_rs[2*c])*mu_rs[2*c+1];
        float a1=(th-mu_rs[2*(64+c)])*mu_rs[2*(64+c)+1];
        float a2=(tw-mu_rs[2*(128+c)])*mu_rs[2*(128+c)+1];
        a0 = a0>=0.f ? a0 : 0.01f*a0;
        a1 = a1>=0.f ? a1 : 0.01f*a1;
        a2 = a2>=0.f ? a2 : 0.01f*a2;
        u0.u[r]=f2bf(a0); u1.u[r]=f2bf(a1); u2.u[r]=f2bf(a2);
        __builtin_amdgcn_sched_barrier(0);   // keep per-channel live ranges from merging
      }
      // k_local = 32*conv + cl0 + 8q -> b_orig = 4*conv + 2*(wave&1) + q
      int bo = ((wave&1)<<1) + q;
      st_act(a_lds, pA, 0 + bo, u0.v);
      st_act(a_lds, pA, 4 + bo, u1.v);
      st_act(a_lds, pA, 8 + bo, u2.v);
    }
    __syncthreads();

    // ---- phase B: A-frags (weights) from global loaded per-kt, B-frags from LDS, 24 MFMA ----
    #pragma unroll
    for (int kt=0; kt<3; ++kt){
      bf16x8 afr[4];
      #pragma unroll
      for (int mt=0; mt<4; ++mt){
        // lane holds W[ch = mt*16+(lane&15)][k = 64*kt + 32g + (lane>>4)*8 + j]
        const float* wp = &w_pw[((mt<<4)+(lane&15))*K_ + (kt<<6) + (g<<5) + ((lane>>4)<<3)];
        f32x4 w0 = *(const f32x4*)wp;
        f32x4 w1 = *(const f32x4*)(wp+4);
        PK cv;
        #pragma unroll
        for (int jj=0;jj<4;jj++){ cv.u[jj]=f2bf(w0[jj]); cv.u[4+jj]=f2bf(w1[jj]); }
        afr[mt] = cv.v;
      }
      #pragma unroll
      for (int nt=0; nt<2; ++nt){
        int p = (wave<<5) + (nt<<4) + (lane&15);
        bf16x8 bfrag = ld_act(a_lds, p, (kt<<2) + (lane>>4));
        #pragma unroll
        for (int mt=0; mt<4; ++mt)
          acc[mt][nt] = __builtin_amdgcn_mfma_f32_16x16x32_bf16(afr[mt], bfrag, acc[mt][nt], 0, 0, 0);
      }
    }
  }

  // ---- epilogue: stores (16-px contiguous per lane-group) + out-channel stats ----
  int base = (d<<14) + (h<<7);
  int p0 = (wave<<5) + (lane&15);
  #pragma unroll
  for (int mt=0; mt<4; ++mt){
    #pragma unroll
    for (int r=0; r<4; ++r){
      int ch = (mt<<4) + ((lane>>4)<<2) + r;
      float v0 = acc[mt][0][r], v1 = acc[mt][1][r];
      out[(ch<<20) + base + p0]      = v0;
      out[(ch<<20) + base + p0 + 16] = v1;
      float s = v0 + v1, qq = v0*v0 + v1*v1;
      atomicAdd(&cstat[((2*ch  )<<3) + (lane&7)], s);
      atomicAdd(&cstat[((2*ch+1)<<3) + (lane&7)], qq);
    }
  }
  __syncthreads();
  if (t < 128){
    float s = 0.f;
    #pragma unroll
    for (int i=0;i<8;i++) s += cstat[(t<<3)+i];
    atomicAdd(&stats_out[t], s);
  }
}

// Pass 3: in-place normalize + LReLU of d_out (float4 vectorized).
__global__ __launch_bounds__(256) void k_norm_out(float* __restrict__ out, const float* __restrict__ mu_rs){
  int i = blockIdx.x*256 + threadIdx.x;   // group of 4 elems
  int c = i >> 18;                         // (i*4) >> 20
  float mu = mu_rs[2*c], rs = mu_rs[2*c+1];
  f32x4 v = ((const f32x4*)out)[i];
  f32x4 r;
  #pragma unroll
  for (int j=0;j<4;j++){
    float f=(v[j]-mu)*rs;
    r[j] = f>=0.f ? f : 0.01f*f;
  }
  ((f32x4*)out)[i] = r;
}

extern "C" void kernel_launch(void* const* d_in, const int* in_sizes, int n_in,
                              void* d_out, int out_size, void* d_ws, size_t ws_size,
                              hipStream_t stream){
  const float* x    = (const float*)d_in[0];
  const float* w_d  = (const float*)d_in[1];
  const float* b_d  = (const float*)d_in[2];
  const float* w_h  = (const float*)d_in[3];
  const float* b_h  = (const float*)d_in[4];
  const float* w_w  = (const float*)d_in[5];
  const float* b_w  = (const float*)d_in[6];
  const float* w_pw = (const float*)d_in[7];
  const float* b_pw = (const float*)d_in[8];
  float* out = (float*)d_out;
  float* ws = (float*)d_ws;
  float* stats_dw  = ws;        // 384 floats
  float* mu_rs_dw  = ws + 384;  // 384 floats
  float* stats_out = ws + 768;  // 128 floats
  float* mu_rs_out = ws + 896;  // 128 floats

  hipMemsetAsync(d_ws, 0, 4096, stream);
  k_dw_stats<<<dim3(D_, C_), 256, 0, stream>>>(x, w_d, w_h, w_w, b_d, b_h, b_w, stats_dw);
  k_finalize<<<1, 256, 0, stream>>>(stats_dw, mu_rs_dw, 192);
  k_pointwise<<<D_*H_, 256, 0, stream>>>(x, w_d, w_h, w_w, b_d, b_h, b_w, w_pw, b_pw,
                                         mu_rs_dw, stats_out, out);
  k_finalize<<<1, 256, 0, stream>>>(stats_out, mu_rs_out, 64);
  k_norm_out<<<(S_/4)*C_/256, 256, 0, stream>>>(out, mu_rs_out);
}

// Round 6
// 1727.826 us; speedup vs baseline: 5.4885x; 5.4885x over previous
//
#include <hip/hip_runtime.h>

typedef unsigned short u16;
typedef __attribute__((ext_vector_type(8))) short bf16x8;
typedef __attribute__((ext_vector_type(4))) float f32x4;

#define C_  64
#define D_  64
#define H_  128
#define W_  128
#define HW_ 16384
#define S_  1048576
#define K_  192

union PK { u16 u[8]; bf16x8 v; };

__device__ __forceinline__ float bf2f(u16 u){
  union { unsigned i; float f; } v; v.i = ((unsigned)u) << 16; return v.f;
}
__device__ __forceinline__ u16 f2bf(float f){
  union { unsigned i; float f; } v; v.f = f;
  unsigned r = v.i + 0x7FFFu + ((v.i >> 16) & 1u);  // round-to-nearest-even
  return (u16)(r >> 16);
}
__device__ __forceinline__ float ldx(const float* __restrict__ x, int c, int d, int h, int w){
  if ((unsigned)d < (unsigned)D_ && (unsigned)h < (unsigned)H_ && (unsigned)w < (unsigned)W_)
    return x[(c<<20) + (d<<14) + (h<<7) + w];
  return 0.f;
}

// t_d: 3x3 over (h,w); t_h: 3x3 over (d,w); t_w: 3x3 over (d,h). 19 unique taps.
__device__ __forceinline__ void compute_tri(
    const float* __restrict__ x, int c, int d, int h, int w,
    const float* wd, const float* wh, const float* ww,
    float& td, float& th, float& tw)
{
  float A00=ldx(x,c,d,h-1,w-1), A01=ldx(x,c,d,h-1,w), A02=ldx(x,c,d,h-1,w+1);
  float A10=ldx(x,c,d,h  ,w-1), A11=ldx(x,c,d,h  ,w), A12=ldx(x,c,d,h  ,w+1);
  float A20=ldx(x,c,d,h+1,w-1), A21=ldx(x,c,d,h+1,w), A22=ldx(x,c,d,h+1,w+1);
  float B00=ldx(x,c,d-1,h,w-1), B01=ldx(x,c,d-1,h,w), B02=ldx(x,c,d-1,h,w+1);
  float B20=ldx(x,c,d+1,h,w-1), B21=ldx(x,c,d+1,h,w), B22=ldx(x,c,d+1,h,w+1);
  float C00=ldx(x,c,d-1,h-1,w), C02=ldx(x,c,d-1,h+1,w);
  float C20=ldx(x,c,d+1,h-1,w), C22=ldx(x,c,d+1,h+1,w);
  td = wd[0]*A00+wd[1]*A01+wd[2]*A02+wd[3]*A10+wd[4]*A11+wd[5]*A12+wd[6]*A20+wd[7]*A21+wd[8]*A22;
  th = wh[0]*B00+wh[1]*B01+wh[2]*B02+wh[3]*A10+wh[4]*A11+wh[5]*A12+wh[6]*B20+wh[7]*B21+wh[8]*B22;
  tw = ww[0]*C00+ww[1]*B01+ww[2]*C02+ww[3]*A01+ww[4]*A11+ww[5]*A21+ww[6]*C20+ww[7]*B21+ww[8]*C22;
}

__device__ __forceinline__ float wave_sum(float v){
  #pragma unroll
  for (int off = 32; off > 0; off >>= 1) v += __shfl_down(v, off, 64);
  return v;
}

// Pass 1: depthwise conv outputs -> per-channel sum / sumsq (192 channels). No tensor writes.
__global__ __launch_bounds__(256) void k_dw_stats(
    const float* __restrict__ x, const float* __restrict__ w_d, const float* __restrict__ w_h,
    const float* __restrict__ w_w, const float* __restrict__ b_d, const float* __restrict__ b_h,
    const float* __restrict__ b_w, float* __restrict__ stats)
{
  int d = blockIdx.x, c = blockIdx.y, t = threadIdx.x;
  float wd[9], wh[9], ww[9];
  #pragma unroll
  for (int i=0;i<9;i++){ wd[i]=w_d[c*9+i]; wh[i]=w_h[c*9+i]; ww[i]=w_w[c*9+i]; }
  float bd=b_d[c], bh=b_h[c], bw=b_w[c];
  float s0=0,q0=0,s1=0,q1=0,s2=0,q2=0;
  for (int idx=t; idx<HW_; idx+=256){
    int h = idx>>7, w = idx&127;
    float td,th,tw;
    compute_tri(x,c,d,h,w,wd,wh,ww,td,th,tw);
    td+=bd; th+=bh; tw+=bw;
    s0+=td; q0+=td*td; s1+=th; q1+=th*th; s2+=tw; q2+=tw*tw;
  }
  s0=wave_sum(s0); q0=wave_sum(q0); s1=wave_sum(s1);
  q1=wave_sum(q1); s2=wave_sum(s2); q2=wave_sum(q2);
  if ((t&63)==0){
    atomicAdd(&stats[2*c],         s0); atomicAdd(&stats[2*c+1],         q0);
    atomicAdd(&stats[2*(64+c)],    s1); atomicAdd(&stats[2*(64+c)+1],    q1);
    atomicAdd(&stats[2*(128+c)],   s2); atomicAdd(&stats[2*(128+c)+1],   q2);
  }
}

__global__ void k_finalize(const float* __restrict__ stats, float* __restrict__ mu_rs, int n){
  int i = threadIdx.x;
  if (i < n){
    const float inv = 1.f/1048576.f;
    float mu  = stats[2*i]*inv;
    float var = stats[2*i+1]*inv - mu*mu;
    mu_rs[2*i]   = mu;
    mu_rs[2*i+1] = rsqrtf(var + 1e-5f);
  }
}

// Activation LDS: [p (128 rows)][k padded to 128 elems], bf16, 16B blocks XOR-swizzled by (p&7).
// Row stride 256 B. Block index b_orig in [0,12) -> b = (b_orig&8) | ((b_orig&7) ^ (p&7)).
__device__ __forceinline__ void st_act1(u16* a_lds, int p, int k, float f){
  int bo = k >> 3;
  int b = (bo & 8) | ((bo & 7) ^ (p & 7));
  a_lds[p*128 + b*8 + (k & 7)] = f2bf(f);
}
__device__ __forceinline__ bf16x8 ld_act(const u16* a_lds, int p, int b_orig){
  int b = (b_orig & 8) | ((b_orig & 7) ^ (p & 7));
  return *(const bf16x8*)((const char*)a_lds + p*256 + b*16);
}

// Pass 2: conv recompute (lane->w coalesced) -> normalized bf16 acts in LDS [p][k] ->
// MFMA pointwise (M=64 ch, N=128 px, K=192 in two 96-chunks) -> fp32 out + out-channel stats.
// Phase A is a NON-unrolled per-channel loop with scalar LDS stores: keeps the live set to
// one channel's taps (~45 VGPR) so the allocator lands ~100-130 VGPR with no cap and no spill.
// (History: fully-unrolled 16-ch phase A needed 256 VGPR [r3, 12% occ]; caps of 4 or 3
// waves/SIMD on that shape spilled to scratch at 22-28 GB [r2, r4].)
__global__ __launch_bounds__(256) void k_pointwise(
    const float* __restrict__ x, const float* __restrict__ w_d, const float* __restrict__ w_h,
    const float* __restrict__ w_w, const float* __restrict__ b_d, const float* __restrict__ b_h,
    const float* __restrict__ b_w, const float* __restrict__ w_pw, const float* __restrict__ b_pw,
    const float* __restrict__ mu_rs, float* __restrict__ stats_out, float* __restrict__ out)
{
  __shared__ __align__(16) u16 a_lds[128*128];   // 32 KB
  __shared__ float cstat[1024];                  // [2*ch + which][8 slots]
  int t = threadIdx.x;
  int lane = t & 63, wave = t >> 6;

  // XCD-chunked swizzle: xcd gets d in [8*xcd, 8*xcd+8), ordered as (4d x 16h) tiles.
  int bid = blockIdx.x;
  int xcd = bid & 7, j = bid >> 3;
  int tile = j >> 6, idx = j & 63;
  int d = (xcd<<3) + ((tile&1)<<2) + (idx>>4);
  int h = ((tile>>1)<<4) + (idx&15);

  for (int i=t; i<1024; i+=256) cstat[i] = 0.f;

  // Accumulators: D[ch][p]. Lane layout (16x16x32): p = p_tile + (lane&15),
  // ch = ch_tile + (lane>>4)*4 + reg. acc[mt][nt], mt: 4 ch-tiles, nt: 2 p-tiles (wave owns 32 px).
  f32x4 acc[4][2];
  #pragma unroll
  for (int mt=0; mt<4; ++mt){
    #pragma unroll
    for (int r=0; r<4; ++r){
      float b = b_pw[(mt<<4) + ((lane>>4)<<2) + r];
      acc[mt][0][r] = b; acc[mt][1][r] = b;
    }
  }

  int pA  = ((wave>>1)<<6) + lane;   // phase-A pixel: waves 0,1 -> 0..63; waves 2,3 -> 64..127
  int cl0 = (wave&1) << 4;           // phase-A channel sub-range within the 32-chunk

  for (int g=0; g<2; ++g){
    if (g) __syncthreads();          // previous chunk's phase-B reads done before overwrite

    // ---- phase A: channels c in [32g+cl0, 32g+cl0+16) for pixel pA, one at a time ----
    #pragma unroll 1
    for (int rr=0; rr<16; ++rr){
      int c = (g<<5) + cl0 + rr;
      float wd[9], wh[9], ww[9];
      #pragma unroll
      for (int i=0;i<9;i++){ wd[i]=w_d[c*9+i]; wh[i]=w_h[c*9+i]; ww[i]=w_w[c*9+i]; }
      float td,th,tw;
      compute_tri(x,c,d,h,pA,wd,wh,ww,td,th,tw);
      td += b_d[c]; th += b_h[c]; tw += b_w[c];
      float a0=(td-mu_rs[2*c])*mu_rs[2*c+1];
      float a1=(th-mu_rs[2*(64+c)])*mu_rs[2*(64+c)+1];
      float a2=(tw-mu_rs[2*(128+c)])*mu_rs[2*(128+c)+1];
      a0 = a0>=0.f ? a0 : 0.01f*a0;
      a1 = a1>=0.f ? a1 : 0.01f*a1;
      a2 = a2>=0.f ? a2 : 0.01f*a2;
      int kl = cl0 + rr;             // k within conv row-block: 0..31
      st_act1(a_lds, pA, kl,      a0);
      st_act1(a_lds, pA, 32 + kl, a1);
      st_act1(a_lds, pA, 64 + kl, a2);
    }
    __syncthreads();

    // ---- phase B: A-frags (weights) from global loaded per-kt, B-frags from LDS, 24 MFMA ----
    #pragma unroll
    for (int kt=0; kt<3; ++kt){
      bf16x8 afr[4];
      #pragma unroll
      for (int mt=0; mt<4; ++mt){
        // lane holds W[ch = mt*16+(lane&15)][k = 64*kt + 32g + (lane>>4)*8 + j]
        const float* wp = &w_pw[((mt<<4)+(lane&15))*K_ + (kt<<6) + (g<<5) + ((lane>>4)<<3)];
        f32x4 w0 = *(const f32x4*)wp;
        f32x4 w1 = *(const f32x4*)(wp+4);
        PK cv;
        #pragma unroll
        for (int jj=0;jj<4;jj++){ cv.u[jj]=f2bf(w0[jj]); cv.u[4+jj]=f2bf(w1[jj]); }
        afr[mt] = cv.v;
      }
      #pragma unroll
      for (int nt=0; nt<2; ++nt){
        int p = (wave<<5) + (nt<<4) + (lane&15);
        bf16x8 bfrag = ld_act(a_lds, p, (kt<<2) + (lane>>4));
        #pragma unroll
        for (int mt=0; mt<4; ++mt)
          acc[mt][nt] = __builtin_amdgcn_mfma_f32_16x16x32_bf16(afr[mt], bfrag, acc[mt][nt], 0, 0, 0);
      }
    }
  }

  // ---- epilogue: stores (16-px contiguous per lane-group) + out-channel stats ----
  int base = (d<<14) + (h<<7);
  int p0 = (wave<<5) + (lane&15);
  #pragma unroll
  for (int mt=0; mt<4; ++mt){
    #pragma unroll
    for (int r=0; r<4; ++r){
      int ch = (mt<<4) + ((lane>>4)<<2) + r;
      float v0 = acc[mt][0][r], v1 = acc[mt][1][r];
      out[(ch<<20) + base + p0]      = v0;
      out[(ch<<20) + base + p0 + 16] = v1;
      float s = v0 + v1, qq = v0*v0 + v1*v1;
      atomicAdd(&cstat[((2*ch  )<<3) + (lane&7)], s);
      atomicAdd(&cstat[((2*ch+1)<<3) + (lane&7)], qq);
    }
  }
  __syncthreads();
  if (t < 128){
    float s = 0.f;
    #pragma unroll
    for (int i=0;i<8;i++) s += cstat[(t<<3)+i];
    atomicAdd(&stats_out[t], s);
  }
}

// Pass 3: in-place normalize + LReLU of d_out (float4 vectorized).
__global__ __launch_bounds__(256) void k_norm_out(float* __restrict__ out, const float* __restrict__ mu_rs){
  int i = blockIdx.x*256 + threadIdx.x;   // group of 4 elems
  int c = i >> 18;                         // (i*4) >> 20
  float mu = mu_rs[2*c], rs = mu_rs[2*c+1];
  f32x4 v = ((const f32x4*)out)[i];
  f32x4 r;
  #pragma unroll
  for (int j=0;j<4;j++){
    float f=(v[j]-mu)*rs;
    r[j] = f>=0.f ? f : 0.01f*f;
  }
  ((f32x4*)out)[i] = r;
}

extern "C" void kernel_launch(void* const* d_in, const int* in_sizes, int n_in,
                              void* d_out, int out_size, void* d_ws, size_t ws_size,
                              hipStream_t stream){
  const float* x    = (const float*)d_in[0];
  const float* w_d  = (const float*)d_in[1];
  const float* b_d  = (const float*)d_in[2];
  const float* w_h  = (const float*)d_in[3];
  const float* b_h  = (const float*)d_in[4];
  const float* w_w  = (const float*)d_in[5];
  const float* b_w  = (const float*)d_in[6];
  const float* w_pw = (const float*)d_in[7];
  const float* b_pw = (const float*)d_in[8];
  float* out = (float*)d_out;
  float* ws = (float*)d_ws;
  float* stats_dw  = ws;        // 384 floats
  float* mu_rs_dw  = ws + 384;  // 384 floats
  float* stats_out = ws + 768;  // 128 floats
  float* mu_rs_out = ws + 896;  // 128 floats

  hipMemsetAsync(d_ws, 0, 4096, stream);
  k_dw_stats<<<dim3(D_, C_), 256, 0, stream>>>(x, w_d, w_h, w_w, b_d, b_h, b_w, stats_dw);
  k_finalize<<<1, 256, 0, stream>>>(stats_dw, mu_rs_dw, 192);
  k_pointwise<<<D_*H_, 256, 0, stream>>>(x, w_d, w_h, w_w, b_d, b_h, b_w, w_pw, b_pw,
                                         mu_rs_dw, stats_out, out);
  k_finalize<<<1, 256, 0, stream>>>(stats_out, mu_rs_out, 64);
  k_norm_out<<<(S_/4)*C_/256, 256, 0, stream>>>(out, mu_rs_out);
}